// Round 6
// baseline (816.199 us; speedup 1.0000x reference)
//
#include <hip/hip_runtime.h>

#define N_NODES 100000
#define N_GRAPHS 64
#define BN_EPS 1e-5
#define NSLICE 8
#define SLICE_SZ ((N_NODES + NSLICE - 1) / NSLICE)   // 12500 nodes per slice
#define CHUNK 4096

// physical XCD id of the CU this block runs on [measured: learn_hip m09]
static __device__ __forceinline__ int get_xcc_id() {
    int x;
    asm volatile("s_getreg_b32 %0, hwreg(HW_REG_XCC_ID)" : "=s"(x));
    return x & (NSLICE - 1);
}

// ---------------- XCD-local in-degree via work stealing ----------------
__global__ void degi_xcd(const int* __restrict__ dst, int* __restrict__ degi,
                         int* __restrict__ work, int E) {
    __shared__ int sh_base;
    int xcd = get_xcc_id();
    int lo = xcd * SLICE_SZ, hi = lo + SLICE_SZ;
    for (;;) {
        if (threadIdx.x == 0) sh_base = atomicAdd(&work[xcd], CHUNK);
        __syncthreads();
        int base = sh_base;
        __syncthreads();
        if (base >= E) break;
        int end = min(base + CHUNK, E);
        for (int e = base + threadIdx.x; e < end; e += 256) {
            int d = dst[e];
            if (d >= lo && d < hi) atomicAdd(&degi[d], 1);
        }
    }
}

// ---------------- XCD-local CSR fill via work stealing ----------------
__global__ void fill_xcd(const int* __restrict__ src, const int* __restrict__ dst,
                         int* __restrict__ cursor, int* __restrict__ nbr,
                         int* __restrict__ work, int E) {
    __shared__ int sh_base;
    int xcd = get_xcc_id();
    int lo = xcd * SLICE_SZ, hi = lo + SLICE_SZ;
    for (;;) {
        if (threadIdx.x == 0) sh_base = atomicAdd(&work[xcd], CHUNK);
        __syncthreads();
        int base = sh_base;
        __syncthreads();
        if (base >= E) break;
        int end = min(base + CHUNK, E);
        for (int e = base + threadIdx.x; e < end; e += 256) {
            int d = dst[e];
            if (d >= lo && d < hi) {
                int p = atomicAdd(&cursor[d], 1);
                nbr[p] = src[e];
            }
        }
    }
}

// ---------------- exclusive scan of degi -> offs (hierarchical) ----------------
__global__ void scan1_kernel(const int* __restrict__ degi, int* __restrict__ offs,
                             int* __restrict__ bsums, int N) {
    __shared__ int sh[256];
    int t = threadIdx.x;
    int base = blockIdx.x * 1024;
    int v[4]; int s = 0;
#pragma unroll
    for (int k = 0; k < 4; ++k) {
        int idx = base + t * 4 + k;
        v[k] = (idx < N) ? degi[idx] : 0;
        s += v[k];
    }
    sh[t] = s;
    __syncthreads();
    for (int st = 1; st < 256; st <<= 1) {
        int val = (t >= st) ? sh[t - st] : 0;
        __syncthreads();
        if (t >= st) sh[t] += val;
        __syncthreads();
    }
    int excl = (t > 0) ? sh[t - 1] : 0;
    if (t == 255) bsums[blockIdx.x] = sh[255];
    int run = excl;
#pragma unroll
    for (int k = 0; k < 4; ++k) {
        int idx = base + t * 4 + k;
        if (idx < N) offs[idx] = run;
        run += v[k];
    }
}

__global__ void scan2_kernel(int* __restrict__ bsums, int nb) {
    if (blockIdx.x == 0 && threadIdx.x == 0) {
        int run = 0;
        for (int i = 0; i < nb; ++i) { int v = bsums[i]; bsums[i] = run; run += v; }
    }
}

__global__ void scan3_kernel(int* __restrict__ offs, const int* __restrict__ bsums,
                             int* __restrict__ cursor, int N, int E) {
    int i = blockIdx.x * blockDim.x + threadIdx.x;
    if (i < N) {
        int v = offs[i] + bsums[i >> 10];
        offs[i] = v;
        cursor[i] = v;
    }
    if (i == 0) offs[N] = E;
}

// ---------------- CSR gather aggregation (double accumulation: order-insensitive) ----------------
__global__ void agg2_kernel(const float2* __restrict__ x, const int* __restrict__ offs,
                            const int* __restrict__ nbr, float2* __restrict__ agg, int N) {
    int n = blockIdx.x * blockDim.x + threadIdx.x;
    if (n >= N) return;
    int beg = offs[n], end = offs[n + 1];
    double ax = 0.0, ay = 0.0;
    for (int j = beg; j < end; ++j) {
        float2 v = x[nbr[j]];
        ax += v.x; ay += v.y;
    }
    agg[n] = make_float2((float)ax, (float)ay);
}

template<int F>
__global__ void agg_csr_v4(const float4* __restrict__ x, const int* __restrict__ offs,
                           const int* __restrict__ nbr, float4* __restrict__ agg, int N) {
    const int FV = F / 4;
    const int NPB = 256 / FV;
    int n = blockIdx.x * NPB + threadIdx.y;
    if (n >= N) return;
    int f = threadIdx.x;
    int beg = offs[n], end = offs[n + 1];
    double ax = 0.0, ay = 0.0, az = 0.0, aw = 0.0;
    for (int j = beg; j < end; ++j) {
        int s = nbr[j];
        float4 v = x[(long long)s * FV + f];
        ax += v.x; ay += v.y; az += v.z; aw += v.w;
    }
    agg[(long long)n * FV + f] = make_float4((float)ax, (float)ay, (float)az, (float)aw);
}

// ---------------- layer-1 linear (8B rows: naturally coalesced) ----------------
template<int DIN, int DOUT>
__global__ __launch_bounds__(256)
void linear_rt(const float* __restrict__ xin, const float* __restrict__ agg,
               const int* __restrict__ degi,
               const float* __restrict__ Wl, const float* __restrict__ bl,
               const float* __restrict__ Wr, float* __restrict__ hout, int N) {
    int n = blockIdx.x * 256 + threadIdx.x;
    if (n >= N) return;
    float invd = 1.0f / fmaxf((float)degi[n], 1.0f);
    const float* __restrict__ ar = agg + (size_t)n * DIN;
    const float* __restrict__ xp = xin + (size_t)n * DIN;
    float acc[DOUT];
#pragma unroll
    for (int j = 0; j < DOUT; ++j) acc[j] = bl[j];
    float2 av = *(const float2*)ar;
    float2 xv = *(const float2*)xp;
    float a[2] = {av.x * invd, av.y * invd};
    float xr[2] = {xv.x, xv.y};
#pragma unroll
    for (int k = 0; k < DIN; ++k) {
#pragma unroll
        for (int j = 0; j < DOUT; ++j)
            acc[j] += a[k] * Wl[k * DOUT + j] + xr[k] * Wr[k * DOUT + j];
    }
    float4* __restrict__ op = (float4*)(hout + (size_t)n * DOUT);
#pragma unroll
    for (int j4 = 0; j4 < DOUT / 4; ++j4)
        op[j4] = make_float4(acc[4*j4], acc[4*j4+1], acc[4*j4+2], acc[4*j4+3]);
}

// ---------------- LDS-staged tiled linear for layers 2/3 ----------------
template<int DIN, int DOUT, int TN>
__global__ __launch_bounds__(256)
void linear_tiled(const float* __restrict__ xin, const float* __restrict__ agg,
                  const int* __restrict__ degi,
                  const float* __restrict__ Wl, const float* __restrict__ bl,
                  const float* __restrict__ Wr, float* __restrict__ hout, int N) {
    constexpr int JT = 32;
    constexpr int NG = DOUT / JT;
    static_assert(TN * NG == 256, "tile config");
    constexpr int STRIDE = DIN + 1;
    constexpr int DIV4 = DIN / 4;
    __shared__ float shA[TN * STRIDE];
    __shared__ float shX[TN * STRIDE];
    __shared__ float shD[TN];

    int n0 = blockIdx.x * TN;
    const float4* __restrict__ gA = (const float4*)(agg + (size_t)n0 * DIN);
    const float4* __restrict__ gX = (const float4*)(xin + (size_t)n0 * DIN);
    constexpr int NV4 = TN * DIN / 4;
#pragma unroll
    for (int it = 0; it < NV4 / 256; ++it) {
        int i = it * 256 + threadIdx.x;
        int row = i / DIV4;
        int col = (i % DIV4) * 4;
        float4 v = gA[i];
        float* p = &shA[row * STRIDE + col];
        p[0] = v.x; p[1] = v.y; p[2] = v.z; p[3] = v.w;
        float4 u = gX[i];
        float* q = &shX[row * STRIDE + col];
        q[0] = u.x; q[1] = u.y; q[2] = u.z; q[3] = u.w;
    }
    for (int i = threadIdx.x; i < TN; i += 256)
        shD[i] = 1.0f / fmaxf((float)degi[n0 + i], 1.0f);
    __syncthreads();

    int tn = threadIdx.x % TN;
    int jg = __builtin_amdgcn_readfirstlane(threadIdx.x / TN);
    int n = n0 + tn;

    float invd = shD[tn];
    float acc[JT];
#pragma unroll
    for (int j = 0; j < JT; ++j) acc[j] = bl[jg * JT + j];

#pragma unroll 4
    for (int k = 0; k < DIN; ++k) {
        float a  = shA[tn * STRIDE + k] * invd;
        float xv = shX[tn * STRIDE + k];
        const float* __restrict__ wlp = Wl + (size_t)k * DOUT + jg * JT;
        const float* __restrict__ wrp = Wr + (size_t)k * DOUT + jg * JT;
#pragma unroll
        for (int j = 0; j < JT; ++j)
            acc[j] += a * wlp[j] + xv * wrp[j];
    }

    if (n < N) {
        float4* __restrict__ op = (float4*)(hout + (size_t)n * DOUT + jg * JT);
#pragma unroll
        for (int j4 = 0; j4 < JT / 4; ++j4)
            op[j4] = make_float4(acc[4*j4], acc[4*j4+1], acc[4*j4+2], acc[4*j4+3]);
    }
}

// ---------------- BN stats (sum, sumsq per feature), fp64 accumulation ----------------
template<int F>
__global__ void bn_stats_kernel(const float* __restrict__ h, double* __restrict__ sums, int N) {
    const int R = 256 / F;
    int f = threadIdx.x & (F - 1);
    int r = threadIdx.x / F;
    float s = 0.f, sq = 0.f;
    for (int n = blockIdx.x * R + r; n < N; n += gridDim.x * R) {
        float v = h[(long long)n * F + f];
        s += v; sq += v * v;
    }
    __shared__ float sh[512];
    sh[threadIdx.x] = s;
    sh[256 + threadIdx.x] = sq;
    __syncthreads();
    for (int st = R / 2; st > 0; st >>= 1) {
        if (r < st) {
            sh[threadIdx.x] += sh[threadIdx.x + st * F];
            sh[256 + threadIdx.x] += sh[256 + threadIdx.x + st * F];
        }
        __syncthreads();
    }
    if (r == 0) {
        atomicAdd(&sums[f], (double)sh[f]);
        atomicAdd(&sums[F + f], (double)sh[256 + f]);
    }
}

template<int F>
__global__ void bn_finalize_kernel(const double* __restrict__ sums,
                                   const float* __restrict__ gamma, const float* __restrict__ beta,
                                   float* __restrict__ scale, float* __restrict__ shift, int N) {
    int f = threadIdx.x;
    if (f >= F) return;
    double mu  = sums[f] / (double)N;
    double var = sums[F + f] / (double)N - mu * mu;
    if (var < 0.0) var = 0.0;
    double sc = (double)gamma[f] / sqrt(var + BN_EPS);
    scale[f] = (float)sc;
    shift[f] = (float)((double)beta[f] - mu * sc);
}

template<int F>
__global__ void bn_apply_v4(float4* __restrict__ h, const float4* __restrict__ scale,
                            const float4* __restrict__ shift, int total4) {
    int i = blockIdx.x * blockDim.x + threadIdx.x;
    if (i >= total4) return;
    int fv = i & (F / 4 - 1);
    float4 v = h[i];
    float4 sc = scale[fv];
    float4 sf = shift[fv];
    v.x = fmaxf(v.x * sc.x + sf.x, 0.f);
    v.y = fmaxf(v.y * sc.y + sf.y, 0.f);
    v.z = fmaxf(v.z * sc.z + sf.z, 0.f);
    v.w = fmaxf(v.w * sc.w + sf.w, 0.f);
    h[i] = v;
}

// ---------------- parallel pool (double atomics: order-insensitive) ----------------
__global__ void pool_partial(const float* __restrict__ h, const int* __restrict__ batch,
                             double* __restrict__ pooled_d, int N) {
    const int CH = 256;
    int n0 = blockIdx.x * CH;
    if (n0 >= N) return;
    int n1 = min(n0 + CH, N);
    int f = threadIdx.x;  // 128
    int g = batch[n0];
    float acc = 0.f;
    for (int n = n0; n < n1; ++n) {
        int bg = batch[n];
        if (bg != g) {
            atomicAdd(&pooled_d[g * 128 + f], (double)acc);
            acc = 0.f;
            g = bg;
        }
        acc += h[(long long)n * 128 + f];
    }
    atomicAdd(&pooled_d[g * 128 + f], (double)acc);
}

__global__ void pool_finalize(const double* __restrict__ pooled_d, float* __restrict__ pooled,
                              const int* __restrict__ batch, int N) {
    int g = blockIdx.x;
    int f = threadIdx.x;
    int lo = 0, hi = N;
    while (lo < hi) { int m = (lo + hi) >> 1; if (batch[m] < g) lo = m + 1; else hi = m; }
    int start = lo;
    hi = N;
    while (lo < hi) { int m = (lo + hi) >> 1; if (batch[m] < g + 1) lo = m + 1; else hi = m; }
    int cnt = lo - start;
    pooled[g * 128 + f] = (float)(pooled_d[g * 128 + f] / (double)max(cnt, 1));
}

// ---------------- head MLP ----------------
__global__ void mlp_kernel(const float* __restrict__ pooled,
                           const float* __restrict__ Wf1, const float* __restrict__ bf1,
                           const float* __restrict__ Wf2, const float* __restrict__ bf2,
                           float* __restrict__ out) {
    int g = blockIdx.x;
    int j = threadIdx.x;  // 64 hidden
    float hacc = bf1[j];
#pragma unroll 8
    for (int k = 0; k < 128; ++k) hacc += pooled[g * 128 + k] * Wf1[k * 64 + j];
    hacc = fmaxf(hacc, 0.f) * Wf2[j];
    for (int off = 32; off > 0; off >>= 1) hacc += __shfl_down(hacc, off);
    if (j == 0) out[g] = hacc + bf2[0];
}

extern "C" void kernel_launch(void* const* d_in, const int* in_sizes, int n_in,
                              void* d_out, int out_size, void* d_ws, size_t ws_size,
                              hipStream_t stream) {
    const float* x     = (const float*)d_in[0];
    const int*   ei    = (const int*)d_in[1];
    const int*   batch = (const int*)d_in[2];
    const float *Wl1=(const float*)d_in[3],  *bl1=(const float*)d_in[4],  *Wr1=(const float*)d_in[5];
    const float *g1 =(const float*)d_in[6],  *be1=(const float*)d_in[7];
    const float *Wl2=(const float*)d_in[8],  *bl2=(const float*)d_in[9],  *Wr2=(const float*)d_in[10];
    const float *g2 =(const float*)d_in[11], *be2=(const float*)d_in[12];
    const float *Wl3=(const float*)d_in[13], *bl3=(const float*)d_in[14], *Wr3=(const float*)d_in[15];
    const float *g3 =(const float*)d_in[16], *be3=(const float*)d_in[17];
    const float *Wf1=(const float*)d_in[18], *bf1=(const float*)d_in[19];
    const float *Wf2=(const float*)d_in[20], *bf2=(const float*)d_in[21];

    const int N = N_NODES;
    const int E = in_sizes[1] / 2;
    const int* src = ei;
    const int* dst = ei + E;

    // ---- workspace layout (256B-aligned) ----
    char* ws = (char*)d_ws;
    size_t off = 0;
    auto salloc = [&](size_t bytes) {
        void* p = ws + off;
        off += (bytes + 255) & ~(size_t)255;
        return p;
    };
    int*    degi    = (int*)   salloc((size_t)N * 4);
    int*    offs    = (int*)   salloc((size_t)(N + 1) * 4);
    int*    cursor  = (int*)   salloc((size_t)N * 4);
    int*    bsums   = (int*)   salloc(512);
    int*    work    = (int*)   salloc(256);               // 2 x 8 steal counters
    int*    nbr     = (int*)   salloc((size_t)E * 4);
    float*  aggb    = (float*) salloc((size_t)N * 64 * 4);
    float*  bufA    = (float*) salloc((size_t)N * 128 * 4);
    float*  bufB    = (float*) salloc((size_t)N * 64 * 4);
    double* sums    = (double*)salloc(768 * 8);
    float*  scale   = (float*) salloc(512);
    float*  shift   = (float*) salloc(512);
    double* pooledd = (double*)salloc((size_t)N_GRAPHS * 128 * 8);
    float*  pooled  = (float*) salloc((size_t)N_GRAPHS * 128 * 4);
    (void)ws_size;

    double* sums1 = sums, *sums2 = sums + 256, *sums3 = sums + 512;

    hipMemsetAsync(degi, 0, (size_t)N * 4, stream);
    hipMemsetAsync(work, 0, 256, stream);
    hipMemsetAsync(sums, 0, 768 * 8, stream);
    hipMemsetAsync(pooledd, 0, (size_t)N_GRAPHS * 128 * 8, stream);

    // ---- CSR build (by dst): XCD-local scatter via HW_REG_XCC_ID + work stealing ----
    const int nb = (N + 1023) / 1024;
    degi_xcd<<<2048, 256, 0, stream>>>(dst, degi, work, E);
    scan1_kernel<<<nb, 256, 0, stream>>>(degi, offs, bsums, N);
    scan2_kernel<<<1, 64, 0, stream>>>(bsums, nb);
    scan3_kernel<<<(N + 255) / 256, 256, 0, stream>>>(offs, bsums, cursor, N, E);
    fill_xcd<<<2048, 256, 0, stream>>>(src, dst, cursor, nbr, work + 8, E);

    const int NL = (N + 255) / 256;

    // ---- layer 1: 2 -> 32, in x, out bufA ----
    agg2_kernel<<<NL, 256, 0, stream>>>((const float2*)x, offs, nbr, (float2*)aggb, N);
    linear_rt<2, 32><<<NL, 256, 0, stream>>>(x, aggb, degi, Wl1, bl1, Wr1, bufA, N);
    bn_stats_kernel<32><<<1024, 256, 0, stream>>>(bufA, sums1, N);
    bn_finalize_kernel<32><<<1, 32, 0, stream>>>(sums1, g1, be1, scale, shift, N);
    bn_apply_v4<32><<<(N * 32 / 4 + 255) / 256, 256, 0, stream>>>((float4*)bufA, (const float4*)scale, (const float4*)shift, N * 32 / 4);

    // ---- layer 2: 32 -> 64, in bufA, out bufB ----
    agg_csr_v4<32><<<(N + 31) / 32, dim3(8, 32), 0, stream>>>((const float4*)bufA, offs, nbr, (float4*)aggb, N);
    linear_tiled<32, 64, 128><<<(N + 127) / 128, 256, 0, stream>>>(bufA, aggb, degi, Wl2, bl2, Wr2, bufB, N);
    bn_stats_kernel<64><<<1024, 256, 0, stream>>>(bufB, sums2, N);
    bn_finalize_kernel<64><<<1, 64, 0, stream>>>(sums2, g2, be2, scale, shift, N);
    bn_apply_v4<64><<<(N * 64 / 4 + 255) / 256, 256, 0, stream>>>((float4*)bufB, (const float4*)scale, (const float4*)shift, N * 64 / 4);

    // ---- layer 3: 64 -> 128, in bufB, out bufA ----
    agg_csr_v4<64><<<(N + 15) / 16, dim3(16, 16), 0, stream>>>((const float4*)bufB, offs, nbr, (float4*)aggb, N);
    linear_tiled<64, 128, 64><<<(N + 63) / 64, 256, 0, stream>>>(bufB, aggb, degi, Wl3, bl3, Wr3, bufA, N);
    bn_stats_kernel<128><<<1024, 256, 0, stream>>>(bufA, sums3, N);
    bn_finalize_kernel<128><<<1, 128, 0, stream>>>(sums3, g3, be3, scale, shift, N);
    bn_apply_v4<128><<<(N * 128 / 4 + 255) / 256, 256, 0, stream>>>((float4*)bufA, (const float4*)scale, (const float4*)shift, N * 128 / 4);

    // ---- pool + head ----
    pool_partial<<<(N + 255) / 256, 128, 0, stream>>>(bufA, batch, pooledd, N);
    pool_finalize<<<N_GRAPHS, 128, 0, stream>>>(pooledd, pooled, batch, N);
    mlp_kernel<<<N_GRAPHS, 64, 0, stream>>>(pooled, Wf1, bf1, Wf2, bf2, (float*)d_out);
}

// Round 7
// 708.828 us; speedup vs baseline: 1.1515x; 1.1515x over previous
//
#include <hip/hip_runtime.h>

#define N_NODES 100000
#define N_GRAPHS 64
#define BN_EPS 1e-5
#define NSLICE 8
#define SLICE_SZ ((N_NODES + NSLICE - 1) / NSLICE)
#define CHUNK 4096

static __device__ __forceinline__ int get_xcc_id() {
    int x;
    asm volatile("s_getreg_b32 %0, hwreg(HW_REG_XCC_ID)" : "=s"(x));
    return x & (NSLICE - 1);
}

// ---------------- XCD-local in-degree, NT streaming reads ----------------
__global__ void degi_xcd(const int* __restrict__ dst, int* __restrict__ degi,
                         int* __restrict__ work, int E) {
    __shared__ int sh_base;
    int xcd = get_xcc_id();
    int lo = xcd * SLICE_SZ, hi = lo + SLICE_SZ;
    for (;;) {
        if (threadIdx.x == 0) sh_base = atomicAdd(&work[xcd], CHUNK);
        __syncthreads();
        int base = sh_base;
        __syncthreads();
        if (base >= E) break;
        int end = min(base + CHUNK, E);
        for (int e = base + threadIdx.x; e < end; e += 256) {
            int d = __builtin_nontemporal_load(dst + e);
            if (d >= lo && d < hi) atomicAdd(&degi[d], 1);
        }
    }
}

// ---------------- XCD-local CSR fill, NT streaming reads ----------------
__global__ void fill_xcd(const int* __restrict__ src, const int* __restrict__ dst,
                         int* __restrict__ cursor, int* __restrict__ nbr,
                         int* __restrict__ work, int E) {
    __shared__ int sh_base;
    int xcd = get_xcc_id();
    int lo = xcd * SLICE_SZ, hi = lo + SLICE_SZ;
    for (;;) {
        if (threadIdx.x == 0) sh_base = atomicAdd(&work[xcd], CHUNK);
        __syncthreads();
        int base = sh_base;
        __syncthreads();
        if (base >= E) break;
        int end = min(base + CHUNK, E);
        for (int e = base + threadIdx.x; e < end; e += 256) {
            int d = __builtin_nontemporal_load(dst + e);
            if (d >= lo && d < hi) {
                int sv = __builtin_nontemporal_load(src + e);
                int p = atomicAdd(&cursor[d], 1);
                nbr[p] = sv;
            }
        }
    }
}

// ---------------- exclusive scan of degi -> offs ----------------
__global__ void scan1_kernel(const int* __restrict__ degi, int* __restrict__ offs,
                             int* __restrict__ bsums, int N) {
    __shared__ int sh[256];
    int t = threadIdx.x;
    int base = blockIdx.x * 1024;
    int v[4]; int s = 0;
#pragma unroll
    for (int k = 0; k < 4; ++k) {
        int idx = base + t * 4 + k;
        v[k] = (idx < N) ? degi[idx] : 0;
        s += v[k];
    }
    sh[t] = s;
    __syncthreads();
    for (int st = 1; st < 256; st <<= 1) {
        int val = (t >= st) ? sh[t - st] : 0;
        __syncthreads();
        if (t >= st) sh[t] += val;
        __syncthreads();
    }
    int excl = (t > 0) ? sh[t - 1] : 0;
    if (t == 255) bsums[blockIdx.x] = sh[255];
    int run = excl;
#pragma unroll
    for (int k = 0; k < 4; ++k) {
        int idx = base + t * 4 + k;
        if (idx < N) offs[idx] = run;
        run += v[k];
    }
}

__global__ void scan2_kernel(int* __restrict__ bsums, int nb) {
    if (blockIdx.x == 0 && threadIdx.x == 0) {
        int run = 0;
        for (int i = 0; i < nb; ++i) { int v = bsums[i]; bsums[i] = run; run += v; }
    }
}

__global__ void scan3_kernel(int* __restrict__ offs, const int* __restrict__ bsums,
                             int* __restrict__ cursor, int N, int E) {
    int i = blockIdx.x * blockDim.x + threadIdx.x;
    if (i < N) {
        int v = offs[i] + bsums[i >> 10];
        offs[i] = v;
        cursor[i] = v;
    }
    if (i == 0) offs[N] = E;
}

// ---------------- layer-1 aggregation (raw x, no BN) ----------------
__global__ void agg2_kernel(const float2* __restrict__ x, const int* __restrict__ offs,
                            const int* __restrict__ nbr, float2* __restrict__ agg, int N) {
    int n = blockIdx.x * blockDim.x + threadIdx.x;
    if (n >= N) return;
    int beg = offs[n], end = offs[n + 1];
    double ax = 0.0, ay = 0.0;
    for (int j = beg; j < end; ++j) {
        float2 v = x[__builtin_nontemporal_load(nbr + j)];
        ax += v.x; ay += v.y;
    }
    agg[n] = make_float2((float)ax, (float)ay);
}

// ---------------- CSR gather agg with fused BN+ReLU on the gathered rows ----------------
template<int F>
__global__ void agg_csr_bn(const float4* __restrict__ x, const int* __restrict__ offs,
                           const int* __restrict__ nbr,
                           const float* __restrict__ scale, const float* __restrict__ shift,
                           float4* __restrict__ agg, int N) {
    const int FV = F / 4;
    const int NPB = 256 / FV;
    int n = blockIdx.x * NPB + threadIdx.y;
    if (n >= N) return;
    int f = threadIdx.x;
    float4 sc = ((const float4*)scale)[f];
    float4 sf = ((const float4*)shift)[f];
    int beg = offs[n], end = offs[n + 1];
    double ax = 0.0, ay = 0.0, az = 0.0, aw = 0.0;
    for (int j = beg; j < end; ++j) {
        int s = __builtin_nontemporal_load(nbr + j);
        float4 v = x[(long long)s * FV + f];
        ax += fmaxf(v.x * sc.x + sf.x, 0.f);
        ay += fmaxf(v.y * sc.y + sf.y, 0.f);
        az += fmaxf(v.z * sc.z + sf.z, 0.f);
        aw += fmaxf(v.w * sc.w + sf.w, 0.f);
    }
    agg[(long long)n * FV + f] = make_float4((float)ax, (float)ay, (float)az, (float)aw);
}

// ---------------- layer-1 linear ----------------
template<int DIN, int DOUT>
__global__ __launch_bounds__(256)
void linear_rt(const float* __restrict__ xin, const float* __restrict__ agg,
               const int* __restrict__ degi,
               const float* __restrict__ Wl, const float* __restrict__ bl,
               const float* __restrict__ Wr, float* __restrict__ hout, int N) {
    int n = blockIdx.x * 256 + threadIdx.x;
    if (n >= N) return;
    float invd = 1.0f / fmaxf((float)degi[n], 1.0f);
    float acc[DOUT];
#pragma unroll
    for (int j = 0; j < DOUT; ++j) acc[j] = bl[j];
    float2 av = *(const float2*)(agg + (size_t)n * DIN);
    float2 xv = *(const float2*)(xin + (size_t)n * DIN);
    float a[2] = {av.x * invd, av.y * invd};
    float xr[2] = {xv.x, xv.y};
#pragma unroll
    for (int k = 0; k < DIN; ++k) {
#pragma unroll
        for (int j = 0; j < DOUT; ++j)
            acc[j] += a[k] * Wl[k * DOUT + j] + xr[k] * Wr[k * DOUT + j];
    }
    float4* __restrict__ op = (float4*)(hout + (size_t)n * DOUT);
#pragma unroll
    for (int j4 = 0; j4 < DOUT / 4; ++j4)
        op[j4] = make_float4(acc[4*j4], acc[4*j4+1], acc[4*j4+2], acc[4*j4+3]);
}

// ---------------- tiled linear v2: single LDS tile, two k-passes ----------------
// pass 1: agg path (pre-scaled by invd); pass 2: x path with fused input-BN+ReLU.
template<int DIN, int DOUT, int TN>
__global__ __launch_bounds__(256)
void linear_tiled2(const float* __restrict__ xin, const float* __restrict__ agg,
                   const int* __restrict__ degi,
                   const float* __restrict__ Wl, const float* __restrict__ bl,
                   const float* __restrict__ Wr,
                   const float* __restrict__ scIn, const float* __restrict__ sfIn,
                   float* __restrict__ hout, int N) {
    constexpr int JT = 32;
    constexpr int NG = DOUT / JT;
    static_assert(TN * NG == 256, "tile config");
    constexpr int STRIDE = DIN + 1;
    constexpr int DIV4 = DIN / 4;
    constexpr int NV4 = TN * DIN / 4;
    __shared__ float shT[TN * STRIDE];
    __shared__ float shD[TN];

    int n0 = blockIdx.x * TN;
    int tid = threadIdx.x;

    // stage agg tile
    const float4* __restrict__ gA = (const float4*)(agg + (size_t)n0 * DIN);
#pragma unroll
    for (int it = 0; it < NV4 / 256; ++it) {
        int i = it * 256 + tid;
        int row = i / DIV4, col = (i % DIV4) * 4;
        float4 v = gA[i];
        float* p = &shT[row * STRIDE + col];
        p[0] = v.x; p[1] = v.y; p[2] = v.z; p[3] = v.w;
    }
    for (int i = tid; i < TN; i += 256)
        shD[i] = 1.0f / fmaxf((float)degi[n0 + i], 1.0f);
    __syncthreads();

    int tn = tid % TN;
    int jg = __builtin_amdgcn_readfirstlane(tid / TN);
    float invd = shD[tn];
    float acc[JT];
#pragma unroll
    for (int j = 0; j < JT; ++j) acc[j] = bl[jg * JT + j];

#pragma unroll 4
    for (int k = 0; k < DIN; ++k) {
        float a = shT[tn * STRIDE + k] * invd;
        const float* __restrict__ wlp = Wl + (size_t)k * DOUT + jg * JT;
#pragma unroll
        for (int j = 0; j < JT; ++j) acc[j] += a * wlp[j];
    }
    __syncthreads();

    // stage x tile with fused BN+ReLU of the input
    const float4* __restrict__ gX = (const float4*)(xin + (size_t)n0 * DIN);
#pragma unroll
    for (int it = 0; it < NV4 / 256; ++it) {
        int i = it * 256 + tid;
        int row = i / DIV4, col4 = i % DIV4;
        float4 u = gX[i];
        float4 sc = ((const float4*)scIn)[col4];
        float4 sf = ((const float4*)sfIn)[col4];
        u.x = fmaxf(u.x * sc.x + sf.x, 0.f);
        u.y = fmaxf(u.y * sc.y + sf.y, 0.f);
        u.z = fmaxf(u.z * sc.z + sf.z, 0.f);
        u.w = fmaxf(u.w * sc.w + sf.w, 0.f);
        float* q = &shT[row * STRIDE + col4 * 4];
        q[0] = u.x; q[1] = u.y; q[2] = u.z; q[3] = u.w;
    }
    __syncthreads();

#pragma unroll 4
    for (int k = 0; k < DIN; ++k) {
        float xv = shT[tn * STRIDE + k];
        const float* __restrict__ wrp = Wr + (size_t)k * DOUT + jg * JT;
#pragma unroll
        for (int j = 0; j < JT; ++j) acc[j] += xv * wrp[j];
    }

    if (n0 + tn < N) {
        float4* __restrict__ op = (float4*)(hout + (size_t)(n0 + tn) * DOUT + jg * JT);
#pragma unroll
        for (int j4 = 0; j4 < JT / 4; ++j4)
            op[j4] = make_float4(acc[4*j4], acc[4*j4+1], acc[4*j4+2], acc[4*j4+3]);
    }
}

// ---------------- BN stats on pre-BN h ----------------
template<int F>
__global__ void bn_stats_kernel(const float* __restrict__ h, double* __restrict__ sums, int N) {
    const int R = 256 / F;
    int f = threadIdx.x & (F - 1);
    int r = threadIdx.x / F;
    float s = 0.f, sq = 0.f;
    for (int n = blockIdx.x * R + r; n < N; n += gridDim.x * R) {
        float v = h[(long long)n * F + f];
        s += v; sq += v * v;
    }
    __shared__ float sh[512];
    sh[threadIdx.x] = s;
    sh[256 + threadIdx.x] = sq;
    __syncthreads();
    for (int st = R / 2; st > 0; st >>= 1) {
        if (r < st) {
            sh[threadIdx.x] += sh[threadIdx.x + st * F];
            sh[256 + threadIdx.x] += sh[256 + threadIdx.x + st * F];
        }
        __syncthreads();
    }
    if (r == 0) {
        atomicAdd(&sums[f], (double)sh[f]);
        atomicAdd(&sums[F + f], (double)sh[256 + f]);
    }
}

template<int F>
__global__ void bn_finalize_kernel(const double* __restrict__ sums,
                                   const float* __restrict__ gamma, const float* __restrict__ beta,
                                   float* __restrict__ scale, float* __restrict__ shift, int N) {
    int f = threadIdx.x;
    if (f >= F) return;
    double mu  = sums[f] / (double)N;
    double var = sums[F + f] / (double)N - mu * mu;
    if (var < 0.0) var = 0.0;
    double sc = (double)gamma[f] / sqrt(var + BN_EPS);
    scale[f] = (float)sc;
    shift[f] = (float)((double)beta[f] - mu * sc);
}

// ---------------- pool with fused BN3+ReLU (double atomics) ----------------
__global__ void pool_partial(const float* __restrict__ h, const int* __restrict__ batch,
                             const float* __restrict__ scale, const float* __restrict__ shift,
                             double* __restrict__ pooled_d, int N) {
    const int CH = 64;
    int n0 = blockIdx.x * CH;
    if (n0 >= N) return;
    int n1 = min(n0 + CH, N);
    int f = threadIdx.x;  // 128
    float sc = scale[f], sf = shift[f];
    int g = batch[n0];
    float acc = 0.f;
    for (int n = n0; n < n1; ++n) {
        int bg = batch[n];
        if (bg != g) {
            atomicAdd(&pooled_d[g * 128 + f], (double)acc);
            acc = 0.f;
            g = bg;
        }
        acc += fmaxf(h[(long long)n * 128 + f] * sc + sf, 0.f);
    }
    atomicAdd(&pooled_d[g * 128 + f], (double)acc);
}

__global__ void pool_finalize(const double* __restrict__ pooled_d, float* __restrict__ pooled,
                              const int* __restrict__ batch, int N) {
    int g = blockIdx.x;
    int f = threadIdx.x;
    int lo = 0, hi = N;
    while (lo < hi) { int m = (lo + hi) >> 1; if (batch[m] < g) lo = m + 1; else hi = m; }
    int start = lo;
    hi = N;
    while (lo < hi) { int m = (lo + hi) >> 1; if (batch[m] < g + 1) lo = m + 1; else hi = m; }
    int cnt = lo - start;
    pooled[g * 128 + f] = (float)(pooled_d[g * 128 + f] / (double)max(cnt, 1));
}

// ---------------- head MLP ----------------
__global__ void mlp_kernel(const float* __restrict__ pooled,
                           const float* __restrict__ Wf1, const float* __restrict__ bf1,
                           const float* __restrict__ Wf2, const float* __restrict__ bf2,
                           float* __restrict__ out) {
    int g = blockIdx.x;
    int j = threadIdx.x;
    float hacc = bf1[j];
#pragma unroll 8
    for (int k = 0; k < 128; ++k) hacc += pooled[g * 128 + k] * Wf1[k * 64 + j];
    hacc = fmaxf(hacc, 0.f) * Wf2[j];
    for (int off = 32; off > 0; off >>= 1) hacc += __shfl_down(hacc, off);
    if (j == 0) out[g] = hacc + bf2[0];
}

extern "C" void kernel_launch(void* const* d_in, const int* in_sizes, int n_in,
                              void* d_out, int out_size, void* d_ws, size_t ws_size,
                              hipStream_t stream) {
    const float* x     = (const float*)d_in[0];
    const int*   ei    = (const int*)d_in[1];
    const int*   batch = (const int*)d_in[2];
    const float *Wl1=(const float*)d_in[3],  *bl1=(const float*)d_in[4],  *Wr1=(const float*)d_in[5];
    const float *g1 =(const float*)d_in[6],  *be1=(const float*)d_in[7];
    const float *Wl2=(const float*)d_in[8],  *bl2=(const float*)d_in[9],  *Wr2=(const float*)d_in[10];
    const float *g2 =(const float*)d_in[11], *be2=(const float*)d_in[12];
    const float *Wl3=(const float*)d_in[13], *bl3=(const float*)d_in[14], *Wr3=(const float*)d_in[15];
    const float *g3 =(const float*)d_in[16], *be3=(const float*)d_in[17];
    const float *Wf1=(const float*)d_in[18], *bf1=(const float*)d_in[19];
    const float *Wf2=(const float*)d_in[20], *bf2=(const float*)d_in[21];

    const int N = N_NODES;
    const int E = in_sizes[1] / 2;
    const int* src = ei;
    const int* dst = ei + E;

    char* ws = (char*)d_ws;
    size_t off = 0;
    auto salloc = [&](size_t bytes) {
        void* p = ws + off;
        off += (bytes + 255) & ~(size_t)255;
        return p;
    };
    // --- contiguous zero-init region first (one memset) ---
    int*    degi    = (int*)   salloc((size_t)N * 4);            // 400128 (padded)
    int*    work    = (int*)   salloc(256);
    double* sums    = (double*)salloc(768 * 8);
    double* pooledd = (double*)salloc((size_t)N_GRAPHS * 128 * 8);
    size_t zero_bytes = off;
    // --- rest ---
    int*    offs    = (int*)   salloc((size_t)(N + 1) * 4);
    int*    cursor  = (int*)   salloc((size_t)N * 4);
    int*    bsums   = (int*)   salloc(512);
    int*    nbr     = (int*)   salloc((size_t)E * 4);
    float*  aggb    = (float*) salloc((size_t)N * 64 * 4);
    float*  bufA    = (float*) salloc((size_t)N * 128 * 4);
    float*  bufB    = (float*) salloc((size_t)N * 64 * 4);
    float*  scale1  = (float*) salloc(512);
    float*  shift1  = (float*) salloc(512);
    float*  scale2  = (float*) salloc(512);
    float*  shift2  = (float*) salloc(512);
    float*  scale3  = (float*) salloc(512);
    float*  shift3  = (float*) salloc(512);
    float*  pooled  = (float*) salloc((size_t)N_GRAPHS * 128 * 4);
    (void)ws_size;

    double* sums1 = sums, *sums2 = sums + 256, *sums3 = sums + 512;

    hipMemsetAsync(degi, 0, zero_bytes, stream);

    // ---- CSR build (by dst) ----
    const int nb = (N + 1023) / 1024;
    degi_xcd<<<2048, 256, 0, stream>>>(dst, degi, work, E);
    scan1_kernel<<<nb, 256, 0, stream>>>(degi, offs, bsums, N);
    scan2_kernel<<<1, 64, 0, stream>>>(bsums, nb);
    scan3_kernel<<<(N + 255) / 256, 256, 0, stream>>>(offs, bsums, cursor, N, E);
    fill_xcd<<<2048, 256, 0, stream>>>(src, dst, cursor, nbr, work + 8, E);

    const int NL = (N + 255) / 256;

    // ---- layer 1: 2 -> 32 (x raw), out bufA = pre-BN h1 ----
    agg2_kernel<<<NL, 256, 0, stream>>>((const float2*)x, offs, nbr, (float2*)aggb, N);
    linear_rt<2, 32><<<NL, 256, 0, stream>>>(x, aggb, degi, Wl1, bl1, Wr1, bufA, N);
    bn_stats_kernel<32><<<1024, 256, 0, stream>>>(bufA, sums1, N);
    bn_finalize_kernel<32><<<1, 32, 0, stream>>>(sums1, g1, be1, scale1, shift1, N);

    // ---- layer 2: 32 -> 64 (BN1 fused into consumers), out bufB = pre-BN h2 ----
    agg_csr_bn<32><<<(N + 31) / 32, dim3(8, 32), 0, stream>>>((const float4*)bufA, offs, nbr, scale1, shift1, (float4*)aggb, N);
    linear_tiled2<32, 64, 128><<<(N + 127) / 128, 256, 0, stream>>>(bufA, aggb, degi, Wl2, bl2, Wr2, scale1, shift1, bufB, N);
    bn_stats_kernel<64><<<1024, 256, 0, stream>>>(bufB, sums2, N);
    bn_finalize_kernel<64><<<1, 64, 0, stream>>>(sums2, g2, be2, scale2, shift2, N);

    // ---- layer 3: 64 -> 128 (BN2 fused), out bufA = pre-BN h3 ----
    agg_csr_bn<64><<<(N + 15) / 16, dim3(16, 16), 0, stream>>>((const float4*)bufB, offs, nbr, scale2, shift2, (float4*)aggb, N);
    linear_tiled2<64, 128, 64><<<(N + 63) / 64, 256, 0, stream>>>(bufB, aggb, degi, Wl3, bl3, Wr3, scale2, shift2, bufA, N);
    bn_stats_kernel<128><<<1024, 256, 0, stream>>>(bufA, sums3, N);
    bn_finalize_kernel<128><<<1, 128, 0, stream>>>(sums3, g3, be3, scale3, shift3, N);

    // ---- pool (BN3+ReLU fused) + head ----
    pool_partial<<<(N + 63) / 64, 128, 0, stream>>>(bufA, batch, scale3, shift3, pooledd, N);
    pool_finalize<<<N_GRAPHS, 128, 0, stream>>>(pooledd, pooled, batch, N);
    mlp_kernel<<<N_GRAPHS, 64, 0, stream>>>(pooled, Wf1, bf1, Wf2, bf2, (float*)d_out);
}